// Round 1
// baseline (234.476 us; speedup 1.0000x reference)
//
#include <hip/hip_runtime.h>
#include <math.h>

#define NN      512
#define EE      16384
#define NDIM    64
#define HID     128
#define FFD     2048
#define VOCAB   50
#define SEQ     100

// quantum embedding constants: (cos(.05)-sin(.05)), cos(.1), sin(.1)
#define QA 0.94877109112428797
#define QB 0.99500416527802582
#define QC 0.099833416646828155

// ---------------- small elementwise kernels ----------------

__global__ void k_prep(const float* __restrict__ x, float* __restrict__ qx,
                       float* __restrict__ deg) {
    int i = blockIdx.x * 256 + threadIdx.x;
    if (i < NN * NDIM) {
        float v = x[i];
        qx[i] = (float)QA * ((float)QB * v + (float)QC * tanhf(v));
    }
    if (i < NN) deg[i] = 1.0f;  // self-loop
}

__global__ void k_deg(const int* __restrict__ ei, float* __restrict__ deg) {
    int e = blockIdx.x * 256 + threadIdx.x;
    if (e < EE) atomicAdd(&deg[ei[EE + e]], 1.0f);
}

__global__ void k_dinv(float* __restrict__ deg) {
    int i = blockIdx.x * 256 + threadIdx.x;
    if (i < NN) deg[i] = rsqrtf(deg[i]);
}

__global__ void k_zero(float* __restrict__ p, int n) {
    int i = blockIdx.x * 256 + threadIdx.x;
    if (i < n) p[i] = 0.0f;
}

__global__ void k_fill_bias(float* __restrict__ p, const float* __restrict__ b) {
    int i = blockIdx.x * 256 + threadIdx.x;  // NN*HID
    p[i] = b[i & (HID - 1)];
}

__global__ void k_bias_relu(const float* __restrict__ agg, const float* __restrict__ b,
                            float* __restrict__ h) {
    int i = blockIdx.x * 256 + threadIdx.x;  // NN*HID
    h[i] = fmaxf(agg[i] + b[i & (HID - 1)], 0.0f);
}

// ---------------- GCN aggregation ----------------

__global__ void k_agg_self(const float* __restrict__ pre, const float* __restrict__ dinv,
                           float* __restrict__ agg) {
    int i = blockIdx.x * 256 + threadIdx.x;  // NN*HID
    int n = i >> 7;
    float di = dinv[n];
    agg[i] = pre[i] * di * di;
}

__global__ void k_agg_edges(const float* __restrict__ pre, const float* __restrict__ dinv,
                            const int* __restrict__ ei, float* __restrict__ agg) {
    // 2 edges per block of 256
    int e = blockIdx.x * 2 + (threadIdx.x >> 7);
    int j = threadIdx.x & 127;
    int s = ei[e];
    int d = ei[EE + e];
    float w = dinv[s] * dinv[d];
    atomicAdd(&agg[d * HID + j], pre[s * HID + j] * w);
}

// ---------------- GEMMs (fp32, latency-tolerant simple tiling) ----------------

// out[M=512, 128] = A[512, K] @ W[K, 128] (+ bias). 256 thr: col=tid&127, 2 row-groups.
template <int K>
__global__ void k_gemm(const float* __restrict__ A, const float* __restrict__ W,
                       const float* __restrict__ b, float* __restrict__ out) {
    const int RPT = 4;
    int col  = threadIdx.x & 127;
    int row0 = (blockIdx.x * 2 + (threadIdx.x >> 7)) * RPT;  // grid 64 -> rows 0..511
    float bias = b ? b[col] : 0.0f;
    float acc[RPT];
#pragma unroll
    for (int r = 0; r < RPT; r++) acc[r] = bias;
    for (int k = 0; k < K; k++) {
        float w = W[k * HID + col];
#pragma unroll
        for (int r = 0; r < RPT; r++) acc[r] = fmaf(A[(row0 + r) * K + k], w, acc[r]);
    }
#pragma unroll
    for (int r = 0; r < RPT; r++) out[(row0 + r) * HID + col] = acc[r];
}

// mid[512,2048] = relu(A[512,128] @ W[128,2048] + b). grid 512: 8 col-chunks x 64 row-groups.
__global__ void k_ff1(const float* __restrict__ A, const float* __restrict__ W,
                      const float* __restrict__ b, float* __restrict__ out) {
    const int RPT = 8;
    int chunk = blockIdx.x & 7;
    int row0  = (blockIdx.x >> 3) * RPT;
    int col   = chunk * 256 + threadIdx.x;
    float bias = b[col];
    float acc[RPT];
#pragma unroll
    for (int r = 0; r < RPT; r++) acc[r] = bias;
#pragma unroll 4
    for (int k = 0; k < HID; k++) {
        float w = W[k * FFD + col];
#pragma unroll
        for (int r = 0; r < RPT; r++) acc[r] = fmaf(A[(row0 + r) * HID + k], w, acc[r]);
    }
#pragma unroll
    for (int r = 0; r < RPT; r++) out[(row0 + r) * FFD + col] = fmaxf(acc[r], 0.0f);
}

// out[512,128] += A[512,2048] @ W[2048,128], split-K atomic. out pre-filled with bias.
__global__ void k_ff2(const float* __restrict__ A, const float* __restrict__ W,
                      float* __restrict__ out) {
    const int RPT = 8, KSPLIT = 8, KC = FFD / KSPLIT;  // 256
    int col  = threadIdx.x & 127;
    int half = threadIdx.x >> 7;
    int ks   = blockIdx.x & 7;
    int row0 = ((blockIdx.x >> 3) * 2 + half) * RPT;  // grid 256 -> 32 row-blocks x 8 ks
    int k0   = ks * KC;
    float acc[RPT];
#pragma unroll
    for (int r = 0; r < RPT; r++) acc[r] = 0.0f;
    for (int k = k0; k < k0 + KC; k++) {
        float w = W[k * HID + col];
#pragma unroll
        for (int r = 0; r < RPT; r++) acc[r] = fmaf(A[(row0 + r) * FFD + k], w, acc[r]);
    }
#pragma unroll
    for (int r = 0; r < RPT; r++) atomicAdd(&out[(row0 + r) * HID + col], acc[r]);
}

// ---------------- residual add + layernorm (one row per block, 128 thr) ----------------

__global__ void k_add_ln(const float* __restrict__ a, const float* __restrict__ c,
                         const float* __restrict__ lw, const float* __restrict__ lb,
                         float* __restrict__ out) {
    int row = blockIdx.x;
    int j = threadIdx.x;
    float v = a[row * HID + j] + c[row * HID + j];
    float s1 = v, s2 = v * v;
#pragma unroll
    for (int o = 32; o > 0; o >>= 1) {
        s1 += __shfl_down(s1, o);
        s2 += __shfl_down(s2, o);
    }
    __shared__ float sh[4];
    int lane = j & 63, wv = j >> 6;
    if (lane == 0) { sh[wv] = s1; sh[2 + wv] = s2; }
    __syncthreads();
    float mean = (sh[0] + sh[1]) * (1.0f / HID);
    float m2   = (sh[2] + sh[3]) * (1.0f / HID);
    float rstd = rsqrtf(m2 - mean * mean + 1e-5f);
    out[row * HID + j] = (v - mean) * rstd * lw[j] + lb[j];
}

// ---------------- output ----------------

__global__ void k_logits(const float* __restrict__ t, const float* __restrict__ W,
                         const float* __restrict__ b, float* __restrict__ out) {
    int i = blockIdx.x * 256 + threadIdx.x;
    if (i >= NN * VOCAB) return;
    int row = i / VOCAB, col = i - row * VOCAB;
    float acc = b[col];
#pragma unroll 8
    for (int k = 0; k < HID; k++) acc = fmaf(t[row * HID + k], W[k * VOCAB + col], acc);
    out[i] = acc;
}

__global__ void k_broadcast(const float* __restrict__ logits, float* __restrict__ out) {
    int i = blockIdx.x * 256 + threadIdx.x;
    if (i < SEQ * NN * VOCAB) out[i] = logits[i % (NN * VOCAB)];
}

// ---------------- launch ----------------

extern "C" void kernel_launch(void* const* d_in, const int* in_sizes, int n_in,
                              void* d_out, int out_size, void* d_ws, size_t ws_size,
                              hipStream_t stream) {
    const float* x   = (const float*)d_in[0];
    const int*   ei  = (const int*)d_in[1];
    const float* g1w = (const float*)d_in[2];
    const float* g1b = (const float*)d_in[3];
    const float* g2w = (const float*)d_in[4];
    const float* g2b = (const float*)d_in[5];
    const float* fcw = (const float*)d_in[6];
    const float* fcb = (const float*)d_in[7];
    const float* saw = (const float*)d_in[8];
    const float* sab = (const float*)d_in[9];
    const float* caw = (const float*)d_in[10];
    const float* cab = (const float*)d_in[11];
    const float* lnw = (const float*)d_in[12];
    const float* lnb = (const float*)d_in[13];
    const float* fw1 = (const float*)d_in[14];
    const float* fb1 = (const float*)d_in[15];
    const float* fw2 = (const float*)d_in[16];
    const float* fb2 = (const float*)d_in[17];
    const float* ow  = (const float*)d_in[18];
    const float* ob  = (const float*)d_in[19];
    float* out = (float*)d_out;

    // workspace layout (floats); total ~1.70M floats = 6.8 MB
    float* ws   = (float*)d_ws;
    float* qx   = ws;                 // 32768
    float* deg  = ws + 32768;         // 512 (becomes dinv)
    float* pre  = ws + 33280;         // 65536
    float* agg  = ws + 98816;         // 65536
    float* h    = ws + 164352;        // 65536
    float* memv = ws + 229888;        // 65536
    float* t    = ws + 295424;        // 65536
    float* tmp2 = ws + 360960;        // 65536
    float* tmp3 = ws + 426496;        // 65536
    float* ca   = ws + 492032;        // 2*65536
    float* mid  = ws + 623104;        // 512*2048
    float* lg   = ws + 1671680;       // 25600

    // ---- GCN front-end ----
    k_prep<<<128, 256, 0, stream>>>(x, qx, deg);
    k_deg<<<64, 256, 0, stream>>>(ei, deg);
    k_dinv<<<2, 256, 0, stream>>>(deg);

    k_gemm<NDIM><<<64, 256, 0, stream>>>(qx, g1w, nullptr, pre);
    k_agg_self<<<256, 256, 0, stream>>>(pre, deg, agg);
    k_agg_edges<<<EE / 2, 256, 0, stream>>>(pre, deg, ei, agg);
    k_bias_relu<<<256, 256, 0, stream>>>(agg, g1b, h);

    k_gemm<HID><<<64, 256, 0, stream>>>(h, g2w, nullptr, pre);
    k_agg_self<<<256, 256, 0, stream>>>(pre, deg, agg);
    k_agg_edges<<<EE / 2, 256, 0, stream>>>(pre, deg, ei, agg);
    k_bias_relu<<<256, 256, 0, stream>>>(agg, g2b, h);

    k_gemm<HID><<<64, 256, 0, stream>>>(h, fcw, fcb, memv);

    // ---- cross-attn is s-independent and q/k-free: ca_l = (mem@w2+b2)@w3+b3 ----
    for (int l = 0; l < 2; l++) {
        const float* w2 = caw + (size_t)(l * 4 + 2) * HID * HID;
        const float* b2 = cab + (size_t)(l * 4 + 2) * HID;
        const float* w3 = caw + (size_t)(l * 4 + 3) * HID * HID;
        const float* b3 = cab + (size_t)(l * 4 + 3) * HID;
        k_gemm<HID><<<64, 256, 0, stream>>>(memv, w2, b2, tmp2);
        k_gemm<HID><<<64, 256, 0, stream>>>(tmp2, w3, b3, ca + (size_t)l * NN * HID);
    }

    // ---- decoder (seq dim degenerate; per-node vectors) ----
    k_zero<<<256, 256, 0, stream>>>(t, NN * HID);
    for (int l = 0; l < 2; l++) {
        const float* sw2 = saw + (size_t)(l * 4 + 2) * HID * HID;
        const float* sb2 = sab + (size_t)(l * 4 + 2) * HID;
        const float* sw3 = saw + (size_t)(l * 4 + 3) * HID * HID;
        const float* sb3 = sab + (size_t)(l * 4 + 3) * HID;
        // self-attn == (t@w2+b2)@w3+b3 (uniform softmax over identical rows)
        k_gemm<HID><<<64, 256, 0, stream>>>(t, sw2, sb2, tmp2);
        k_gemm<HID><<<64, 256, 0, stream>>>(tmp2, sw3, sb3, tmp3);
        k_add_ln<<<NN, HID, 0, stream>>>(t, tmp3, lnw + (l * 3 + 0) * HID,
                                         lnb + (l * 3 + 0) * HID, t);
        // cross-attn (precomputed)
        k_add_ln<<<NN, HID, 0, stream>>>(t, ca + (size_t)l * NN * HID,
                                         lnw + (l * 3 + 1) * HID,
                                         lnb + (l * 3 + 1) * HID, t);
        // FF
        k_ff1<<<512, 256, 0, stream>>>(t, fw1 + (size_t)l * HID * FFD,
                                       fb1 + (size_t)l * FFD, mid);
        k_fill_bias<<<256, 256, 0, stream>>>(tmp3, fb2 + (size_t)l * HID);
        k_ff2<<<256, 256, 0, stream>>>(mid, fw2 + (size_t)l * FFD * HID, tmp3);
        k_add_ln<<<NN, HID, 0, stream>>>(t, tmp3, lnw + (l * 3 + 2) * HID,
                                         lnb + (l * 3 + 2) * HID, t);
    }

    // ---- vocab matmul + broadcast over SEQ ----
    k_logits<<<(NN * VOCAB + 255) / 256, 256, 0, stream>>>(t, ow, ob, lg);
    k_broadcast<<<(SEQ * NN * VOCAB + 255) / 256, 256, 0, stream>>>(lg, out);
}

// Round 2
// 152.551 us; speedup vs baseline: 1.5370x; 1.5370x over previous
//
#include <hip/hip_runtime.h>
#include <math.h>

#define NN      512
#define EE      16384
#define NDIM    64
#define HID     128
#define FFD     2048
#define VOCAB   50
#define SEQ     100

// quantum embedding constants: (cos(.05)-sin(.05)), cos(.1), sin(.1)
#define QA 0.94877109112428797f
#define QB 0.99500416527802582f
#define QC 0.099833416646828155f

// ---------------- prep: quantum embedding + zero CSR counters ----------------

__global__ void k_prep(const float* __restrict__ x, float* __restrict__ qx,
                       int* __restrict__ cnt) {
    int i = blockIdx.x * 256 + threadIdx.x;
    if (i < NN * NDIM) {
        float v = x[i];
        qx[i] = QA * (QB * v + QC * tanhf(v));
    }
    if (i < NN) cnt[i] = 0;
}

__global__ void k_hist(const int* __restrict__ ei, int* __restrict__ cnt) {
    int e = blockIdx.x * 256 + threadIdx.x;
    if (e < EE) atomicAdd(&cnt[ei[EE + e]], 1);
}

// 1 block, 512 threads: exclusive-scan counts -> offs, cursor; dinv = rsqrt(cnt+1)
__global__ void k_scan(const int* __restrict__ cnt, int* __restrict__ offs,
                       int* __restrict__ cursor, float* __restrict__ dinv) {
    __shared__ int sh[512];
    int t = threadIdx.x;
    int c = cnt[t];
    sh[t] = c;
    __syncthreads();
    int v = c;
    for (int o = 1; o < 512; o <<= 1) {
        int add = (t >= o) ? sh[t - o] : 0;
        __syncthreads();
        v += add;
        sh[t] = v;
        __syncthreads();
    }
    offs[t + 1] = v;          // inclusive
    if (t == 0) offs[0] = 0;
    cursor[t] = v - c;        // exclusive
    dinv[t] = rsqrtf((float)c + 1.0f);
}

__global__ void k_scatter(const int* __restrict__ ei, int* __restrict__ cursor,
                          int* __restrict__ csr) {
    int e = blockIdx.x * 256 + threadIdx.x;
    if (e < EE) {
        int d = ei[EE + e];
        int slot = atomicAdd(&cursor[d], 1);
        csr[slot] = ei[e];    // store src
    }
}

// ---------------- weight combining: out[129][128] = [A;ab] @ B (+ [0;bb]) ----------------
// rows 0..127: A@B ; row 128: ab@B + bb   (so (x@A+ab)@B+bb == x@out[0:128] + out[128])

struct CombArgs {
    const float* A[4];
    const float* ab[4];
    const float* B[4];
    const float* bb[4];
    float*       out[4];
};

__global__ void k_comb(CombArgs c) {
    int j = blockIdx.y;
    int i = blockIdx.x * 256 + threadIdx.x;   // 129*128 = 16512
    if (i >= 129 * HID) return;
    int row = i >> 7, col = i & 127;
    const float* B = c.B[j];
    float acc;
    if (row < 128) {
        const float* a = c.A[j] + row * HID;
        acc = 0.0f;
#pragma unroll 8
        for (int k = 0; k < HID; k++) acc = fmaf(a[k], B[k * HID + col], acc);
    } else {
        const float* ab = c.ab[j];
        acc = c.bb[j][col];
#pragma unroll 8
        for (int k = 0; k < HID; k++) acc = fmaf(ab[k], B[k * HID + col], acc);
    }
    c.out[j][i] = acc;
}

// ---------------- GEMMs ----------------

// pre[512,128] = A[512,K] @ W[K,128]; 1 output/thread, grid 256
template <int K>
__global__ void k_gcn_mm(const float* __restrict__ A, const float* __restrict__ W,
                         float* __restrict__ out) {
    int i = blockIdx.x * 256 + threadIdx.x;
    int row = i >> 7, col = i & 127;
    const float* a = A + row * K;
    float acc = 0.0f;
#pragma unroll 8
    for (int k = 0; k < K; k++) acc = fmaf(a[k], W[k * HID + col], acc);
    out[i] = acc;
}

// out[512,128] = A[512,128] @ M[0:128] + M[128] (combined bias row); grid.y slices
struct MMArgs { const float* M[2]; float* out[2]; };

__global__ void k_gemm_M(const float* __restrict__ A, MMArgs args) {
    const float* M = args.M[blockIdx.y];
    float* out = args.out[blockIdx.y];
    int i = blockIdx.x * 256 + threadIdx.x;
    int row = i >> 7, col = i & 127;
    const float* a = A + row * HID;
    float acc = M[128 * HID + col];
#pragma unroll 8
    for (int k = 0; k < HID; k++) acc = fmaf(a[k], M[k * HID + col], acc);
    out[i] = acc;
}

// ---------------- GCN gather: agg + bias + relu ----------------

__global__ void k_gather(const float* __restrict__ pre, const float* __restrict__ dinv,
                         const int* __restrict__ offs, const int* __restrict__ csr,
                         const float* __restrict__ bias, float* __restrict__ hout) {
    int d = blockIdx.x, j = threadIdx.x;
    float dd = dinv[d];
    float acc = pre[d * HID + j] * dd;            // self loop (x dd at end)
    int i = offs[d], e = offs[d + 1];
    for (; i + 3 < e; i += 4) {
        int s0 = csr[i], s1 = csr[i + 1], s2 = csr[i + 2], s3 = csr[i + 3];
        float a0 = pre[s0 * HID + j] * dinv[s0];
        float a1 = pre[s1 * HID + j] * dinv[s1];
        float a2 = pre[s2 * HID + j] * dinv[s2];
        float a3 = pre[s3 * HID + j] * dinv[s3];
        acc += (a0 + a1) + (a2 + a3);
    }
    for (; i < e; ++i) {
        int s = csr[i];
        acc += pre[s * HID + j] * dinv[s];
    }
    hout[d * HID + j] = fmaxf(acc * dd + bias[j], 0.0f);
}

// ---------------- FF ----------------

// mid[512,2048] = relu(A[512,128] @ W[128,2048] + b); grid 512 (8 col-chunks x 64 row-groups)
__global__ void k_ff1(const float* __restrict__ A, const float* __restrict__ W,
                      const float* __restrict__ b, float* __restrict__ out) {
    const int RPT = 8;
    int chunk = blockIdx.x & 7;
    int row0  = (blockIdx.x >> 3) * RPT;
    int col   = chunk * 256 + threadIdx.x;
    float bias = b[col];
    float acc[RPT];
#pragma unroll
    for (int r = 0; r < RPT; r++) acc[r] = bias;
#pragma unroll 4
    for (int k = 0; k < HID; k++) {
        float w = W[k * FFD + col];
#pragma unroll
        for (int r = 0; r < RPT; r++) acc[r] = fmaf(A[(row0 + r) * HID + k], w, acc[r]);
    }
#pragma unroll
    for (int r = 0; r < RPT; r++) out[(row0 + r) * FFD + col] = fmaxf(acc[r], 0.0f);
}

// part[ks][512][128] partials of A[512,2048] @ W[2048,128]; grid 512 (64 rg x 8 ks)
__global__ void k_ff2p(const float* __restrict__ A, const float* __restrict__ W,
                       float* __restrict__ part) {
    const int KC = FFD / 8;     // 256
    int col  = threadIdx.x & 127;
    int half = threadIdx.x >> 7;
    int ks   = blockIdx.x & 7;
    int rg   = blockIdx.x >> 3;             // 0..63
    int row0 = rg * 8 + half * 4;
    int k0   = ks * KC;
    const float* a = A + row0 * FFD + k0;
    float acc[4] = {0.f, 0.f, 0.f, 0.f};
#pragma unroll 4
    for (int k = 0; k < KC; k++) {
        float w = W[(k0 + k) * HID + col];
#pragma unroll
        for (int r = 0; r < 4; r++) acc[r] = fmaf(a[r * FFD + k], w, acc[r]);
    }
#pragma unroll
    for (int r = 0; r < 4; r++) part[ks * (NN * HID) + (row0 + r) * HID + col] = acc[r];
}

// fallback (small ws): atomic accumulate into part[0] (must be zeroed first)
__global__ void k_ff2atom(const float* __restrict__ A, const float* __restrict__ W,
                          float* __restrict__ acc_out) {
    const int KC = FFD / 8;
    int col  = threadIdx.x & 127;
    int half = threadIdx.x >> 7;
    int ks   = blockIdx.x & 7;
    int rg   = blockIdx.x >> 3;
    int row0 = rg * 8 + half * 4;
    int k0   = ks * KC;
    const float* a = A + row0 * FFD + k0;
    float acc[4] = {0.f, 0.f, 0.f, 0.f};
#pragma unroll 4
    for (int k = 0; k < KC; k++) {
        float w = W[(k0 + k) * HID + col];
#pragma unroll
        for (int r = 0; r < 4; r++) acc[r] = fmaf(a[r * FFD + k], w, acc[r]);
    }
#pragma unroll
    for (int r = 0; r < 4; r++) atomicAdd(&acc_out[(row0 + r) * HID + col], acc[r]);
}

__global__ void k_zero(float* __restrict__ p, int n) {
    int i = blockIdx.x * 256 + threadIdx.x;
    if (i < n) p[i] = 0.0f;
}

// ---------------- layernorm helpers / fused kernels ----------------

__device__ __forceinline__ float blockln(float v, float w, float b, float* sh, int j) {
    float s1 = v, s2 = v * v;
#pragma unroll
    for (int o = 32; o > 0; o >>= 1) {
        s1 += __shfl_down(s1, o);
        s2 += __shfl_down(s2, o);
    }
    if ((j & 63) == 0) { sh[j >> 6] = s1; sh[2 + (j >> 6)] = s2; }
    __syncthreads();
    float mean = (sh[0] + sh[1]) * (1.0f / HID);
    float m2   = (sh[2] + sh[3]) * (1.0f / HID);
    __syncthreads();
    float rstd = rsqrtf(m2 - mean * mean + 1e-5f);
    return (v - mean) * rstd * w + b;
}

// out = LN( LN(tin + sa) + ca ); tin nullable (treated as 0); sa stride 0 => broadcast row
__global__ void k_add2ln(const float* __restrict__ tin, const float* __restrict__ sa,
                         int sastride, const float* __restrict__ ca,
                         const float* __restrict__ w0, const float* __restrict__ b0,
                         const float* __restrict__ w1, const float* __restrict__ b1,
                         float* __restrict__ out) {
    __shared__ float sh[4];
    int row = blockIdx.x, j = threadIdx.x;
    float v = sa[row * sastride + j] + (tin ? tin[row * HID + j] : 0.0f);
    v = blockln(v, w0[j], b0[j], sh, j);
    v = v + ca[row * HID + j];
    v = blockln(v, w1[j], b1[j], sh, j);
    out[row * HID + j] = v;
}

// t = LN( t + bias + sum_ks part[ks] )
template <int KS>
__global__ void k_ff2red_ln(const float* __restrict__ part, const float* __restrict__ fb2,
                            const float* __restrict__ tres, const float* __restrict__ w,
                            const float* __restrict__ b, float* __restrict__ out) {
    __shared__ float sh[4];
    int row = blockIdx.x, j = threadIdx.x;
    float v = fb2[j] + tres[row * HID + j];
#pragma unroll
    for (int s = 0; s < KS; s++) v += part[s * (NN * HID) + row * HID + j];
    v = blockln(v, w[j], b[j], sh, j);
    out[row * HID + j] = v;
}

// ---------------- output: logits + broadcast over SEQ ----------------

__global__ void k_logits_bcast(const float* __restrict__ t, const float* __restrict__ W,
                               const float* __restrict__ b, float* __restrict__ out) {
    int tid = threadIdx.x;       // 128, use 100
    if (tid >= 100) return;
    int r = tid / 50, c = tid - r * 50;
    int row = blockIdx.x * 2 + r;            // grid 256 -> rows 0..511
    const float* a = t + row * HID;
    float acc = b[c];
#pragma unroll 8
    for (int k = 0; k < HID; k++) acc = fmaf(a[k], W[k * VOCAB + c], acc);
    float* o = out + row * VOCAB + c;
#pragma unroll 4
    for (int s = 0; s < SEQ; s++) o[s * (NN * VOCAB)] = acc;
}

// ---------------- launch ----------------

extern "C" void kernel_launch(void* const* d_in, const int* in_sizes, int n_in,
                              void* d_out, int out_size, void* d_ws, size_t ws_size,
                              hipStream_t stream) {
    (void)in_sizes; (void)n_in; (void)out_size;
    const float* x   = (const float*)d_in[0];
    const int*   ei  = (const int*)d_in[1];
    const float* g1w = (const float*)d_in[2];
    const float* g1b = (const float*)d_in[3];
    const float* g2w = (const float*)d_in[4];
    const float* g2b = (const float*)d_in[5];
    const float* fcw = (const float*)d_in[6];
    const float* fcb = (const float*)d_in[7];
    const float* saw = (const float*)d_in[8];
    const float* sab = (const float*)d_in[9];
    const float* caw = (const float*)d_in[10];
    const float* cab = (const float*)d_in[11];
    const float* lnw = (const float*)d_in[12];
    const float* lnb = (const float*)d_in[13];
    const float* fw1 = (const float*)d_in[14];
    const float* fb1 = (const float*)d_in[15];
    const float* fw2 = (const float*)d_in[16];
    const float* fb2 = (const float*)d_in[17];
    const float* ow  = (const float*)d_in[18];
    const float* ob  = (const float*)d_in[19];
    float* out = (float*)d_out;

    // workspace layout (float offsets)
    float* ws   = (float*)d_ws;
    float* qx   = ws;                  // 32768
    float* pre  = ws + 32768;          // 65536
    float* h    = ws + 98304;          // 65536
    float* t    = ws + 163840;         // 65536
    float* tmp3 = ws + 229376;         // 65536
    float* ca0  = ws + 294912;         // 65536
    float* ca1  = ws + 360448;         // 65536
    float* Msa0 = ws + 425984;         // 16512 (only bias row used)
    float* Msa1 = ws + 442496;         // 16512
    float* Mca0 = ws + 459008;         // 16512
    float* Mca1 = ws + 475520;         // 16512
    float* Mfc0 = ws + 492032;         // 16512
    float* Mfc1 = ws + 508544;         // 16512
    float* dinv = ws + 525056;         // 512
    int*   cnt    = (int*)(ws + 525568);   // 512
    int*   offs   = cnt + 512;             // 513
    int*   cursor = offs + 513;            // 512
    int*   csr    = cursor + 512;          // 16384
    float* mid  = ws + 543744;         // 1048576
    float* part = ws + 1592320;        // 524288 (or 65536 in fallback)
    bool use8 = ws_size >= (size_t)2116608 * 4;   // 8.47 MB

    // ---- CSR build + embeddings ----
    k_prep<<<128, 256, 0, stream>>>(x, qx, cnt);
    k_hist<<<64, 256, 0, stream>>>(ei, cnt);
    k_scan<<<1, 512, 0, stream>>>(cnt, offs, cursor, dinv);
    k_scatter<<<64, 256, 0, stream>>>(ei, cursor, csr);

    // ---- combined weights ----
    // stage 1: Msa1 = sa1.w2@w3 (+bias); Mca0/1 = ca.w2@w3 (+bias); Msa0 bias row only
    {
        CombArgs c;
        c.A[0] = saw + (1 * 4 + 2) * HID * HID;  c.ab[0] = sab + (1 * 4 + 2) * HID;
        c.B[0] = saw + (1 * 4 + 3) * HID * HID;  c.bb[0] = sab + (1 * 4 + 3) * HID;
        c.out[0] = Msa1;
        c.A[1] = caw + 2 * HID * HID;            c.ab[1] = cab + 2 * HID;
        c.B[1] = caw + 3 * HID * HID;            c.bb[1] = cab + 3 * HID;
        c.out[1] = Mca0;
        c.A[2] = caw + (4 + 2) * HID * HID;      c.ab[2] = cab + (4 + 2) * HID;
        c.B[2] = caw + (4 + 3) * HID * HID;      c.bb[2] = cab + (4 + 3) * HID;
        c.out[2] = Mca1;
        c.A[3] = saw + 2 * HID * HID;            c.ab[3] = sab + 2 * HID;
        c.B[3] = saw + 3 * HID * HID;            c.bb[3] = sab + 3 * HID;
        c.out[3] = Msa0;
        k_comb<<<dim3(65, 4), 256, 0, stream>>>(c);
    }
    // stage 2: Mfc_l = fc @ Mca_l (folds fc layer into cross-attn)
    {
        CombArgs c;
        c.A[0] = fcw; c.ab[0] = fcb; c.B[0] = Mca0; c.bb[0] = Mca0 + 128 * HID; c.out[0] = Mfc0;
        c.A[1] = fcw; c.ab[1] = fcb; c.B[1] = Mca1; c.bb[1] = Mca1 + 128 * HID; c.out[1] = Mfc1;
        c.A[2] = fcw; c.ab[2] = fcb; c.B[2] = Mca0; c.bb[2] = Mca0; c.out[2] = Mfc0;  // unused
        c.A[3] = c.A[2]; c.ab[3] = c.ab[2]; c.B[3] = c.B[2]; c.bb[3] = c.bb[2]; c.out[3] = Mfc0;
        k_comb<<<dim3(65, 2), 256, 0, stream>>>(c);
    }

    // ---- GCN front-end ----
    k_gcn_mm<NDIM><<<256, 256, 0, stream>>>(qx, g1w, pre);
    k_gather<<<NN, HID, 0, stream>>>(pre, dinv, offs, csr, g1b, h);
    k_gcn_mm<HID><<<256, 256, 0, stream>>>(h, g2w, pre);
    k_gather<<<NN, HID, 0, stream>>>(pre, dinv, offs, csr, g2b, h);

    // ---- cross-attn outputs for both layers (fc folded): ca_l = h @ Mfc_l ----
    {
        MMArgs m; m.M[0] = Mfc0; m.M[1] = Mfc1; m.out[0] = ca0; m.out[1] = ca1;
        k_gemm_M<<<dim3(256, 2), 256, 0, stream>>>(h, m);
    }

    // ---- decoder layer 0 (t=0: self-attn == bias row of Msa0) ----
    k_add2ln<<<NN, HID, 0, stream>>>(nullptr, Msa0 + 128 * HID, 0, ca0,
                                     lnw + 0 * HID, lnb + 0 * HID,
                                     lnw + 1 * HID, lnb + 1 * HID, t);
    k_ff1<<<512, 256, 0, stream>>>(t, fw1, fb1, mid);
    if (use8) {
        k_ff2p<<<512, 256, 0, stream>>>(mid, fw2, part);
        k_ff2red_ln<8><<<NN, HID, 0, stream>>>(part, fb2, t, lnw + 2 * HID, lnb + 2 * HID, t);
    } else {
        k_zero<<<256, 256, 0, stream>>>(part, NN * HID);
        k_ff2atom<<<512, 256, 0, stream>>>(mid, fw2, part);
        k_ff2red_ln<1><<<NN, HID, 0, stream>>>(part, fb2, t, lnw + 2 * HID, lnb + 2 * HID, t);
    }

    // ---- decoder layer 1 ----
    {
        MMArgs m; m.M[0] = Msa1; m.M[1] = Msa1; m.out[0] = tmp3; m.out[1] = tmp3;
        k_gemm_M<<<dim3(256, 1), 256, 0, stream>>>(t, m);
    }
    k_add2ln<<<NN, HID, 0, stream>>>(t, tmp3, HID, ca1,
                                     lnw + 3 * HID, lnb + 3 * HID,
                                     lnw + 4 * HID, lnb + 4 * HID, t);
    k_ff1<<<512, 256, 0, stream>>>(t, fw1 + HID * FFD, fb1 + FFD, mid);
    if (use8) {
        k_ff2p<<<512, 256, 0, stream>>>(mid, fw2 + FFD * HID, part);
        k_ff2red_ln<8><<<NN, HID, 0, stream>>>(part, fb2 + HID, t, lnw + 5 * HID, lnb + 5 * HID, t);
    } else {
        k_zero<<<256, 256, 0, stream>>>(part, NN * HID);
        k_ff2atom<<<512, 256, 0, stream>>>(mid, fw2 + FFD * HID, part);
        k_ff2red_ln<1><<<NN, HID, 0, stream>>>(part, fb2 + HID, t, lnw + 5 * HID, lnb + 5 * HID, t);
    }

    // ---- logits + broadcast over SEQ ----
    k_logits_bcast<<<256, 128, 0, stream>>>(t, ow, ob, out);
}

// Round 3
// 113.385 us; speedup vs baseline: 2.0680x; 1.3454x over previous
//
#include <hip/hip_runtime.h>
#include <math.h>

#define NN      512
#define EE      16384
#define NDIM    64
#define HID     128
#define FFD     2048
#define VOCAB   50
#define SEQ     100

// quantum embedding constants: (cos(.05)-sin(.05)), cos(.1), sin(.1)
#define QA 0.94877109112428797f
#define QB 0.99500416527802582f
#define QC 0.099833416646828155f

// ---------------- stage A: quantum embedding + zero CSR counters ----------------

__global__ void k_prep(const float* __restrict__ x, float* __restrict__ qx,
                       int* __restrict__ cnt) {
    int i = blockIdx.x * 256 + threadIdx.x;
    if (i < NN * NDIM) {
        float v = x[i];
        qx[i] = QA * (QB * v + QC * tanhf(v));
    }
    if (i < NN) cnt[i] = 0;
}

// ---------------- stage B: hist | GCN1 mm | comb stage1 (independent) ----------------

struct BArgs {
    const int* ei; int* cnt;
    const float* qx; const float* g1w; float* pre1;
    const float* A[3]; const float* ab[3]; const float* Bm[3]; const float* bb[3];
    float* outM[3];
    const float* ab3; const float* B3; const float* bb3; float* out3;  // Msa0 bias row
};

__global__ void k_b(BArgs a) {
    int B = blockIdx.x, t = threadIdx.x;
    if (B < 64) {                              // hist: 16384 edges
        int e = B * 256 + t;
        atomicAdd(&a.cnt[a.ei[EE + e]], 1);
        return;
    }
    if (B < 320) {                             // GCN1 mm: pre1[512,128] = qx @ g1w
        int i = (B - 64) * 256 + t;
        int row = i >> 7, col = i & 127;
        const float* xr = a.qx + row * NDIM;
        float acc = 0.0f;
#pragma unroll 8
        for (int k = 0; k < NDIM; k++) acc = fmaf(xr[k], a.g1w[k * HID + col], acc);
        a.pre1[i] = acc;
        return;
    }
    if (B < 320 + 195) {                       // comb1: Msa1, Mca0, Mca1 (129x128 each)
        int q = B - 320;
        int jm = q / 65;
        int i = (q - jm * 65) * 256 + t;
        if (i >= 129 * HID) return;
        int rw = i >> 7, col = i & 127;
        const float* Bm = a.Bm[jm];
        float acc;
        if (rw < 128) {
            const float* ar = a.A[jm] + rw * HID;
            acc = 0.0f;
#pragma unroll 8
            for (int k = 0; k < HID; k++) acc = fmaf(ar[k], Bm[k * HID + col], acc);
        } else {
            acc = a.bb[jm][col];
#pragma unroll 8
            for (int k = 0; k < HID; k++) acc = fmaf(a.ab[jm][k], Bm[k * HID + col], acc);
        }
        a.outM[jm][i] = acc;
        return;
    }
    // last block: Msa0 bias row only (layer-0 self-attn of tgt=0 is a constant row)
    if (t < HID) {
        float acc = a.bb3[t];
#pragma unroll 8
        for (int k = 0; k < HID; k++) acc = fmaf(a.ab3[k], a.B3[k * HID + t], acc);
        a.out3[t] = acc;
    }
}

// ---------------- stage C: scan (block 0) | comb stage2 (fold fc into ca) ----------------

struct CArgs {
    const int* cnt; int* offs; int* cursor; float* dinv;
    const float* fcw; const float* fcb;
    const float* Mca0; const float* Mca1; float* Mfc0; float* Mfc1;
};

__global__ void k_c(CArgs a) {
    int B = blockIdx.x, t = threadIdx.x;
    if (B == 0) {                              // inclusive scan of 512 counts, 256 thr
        __shared__ int sh[512];
        int c0 = a.cnt[t], c1 = a.cnt[t + 256];
        sh[t] = c0; sh[t + 256] = c1;
        __syncthreads();
        for (int o = 1; o < 512; o <<= 1) {
            int x0 = (t >= o) ? sh[t - o] : 0;
            int x1 = (t + 256 >= o) ? sh[t + 256 - o] : 0;
            __syncthreads();
            sh[t] += x0; sh[t + 256] += x1;
            __syncthreads();
        }
        a.offs[t + 1] = sh[t];
        a.offs[t + 257] = sh[t + 256];
        if (t == 0) a.offs[0] = 0;
        a.cursor[t] = sh[t] - c0;
        a.cursor[t + 256] = sh[t + 256] - c1;
        a.dinv[t] = rsqrtf((float)c0 + 1.0f);
        a.dinv[t + 256] = rsqrtf((float)c1 + 1.0f);
        return;
    }
    int q = B - 1;
    int jm = q / 65;
    int i = (q - jm * 65) * 256 + t;
    if (i >= 129 * HID) return;
    int rw = i >> 7, col = i & 127;
    const float* M = jm ? a.Mca1 : a.Mca0;
    float* o = jm ? a.Mfc1 : a.Mfc0;
    float acc;
    if (rw < 128) {
        const float* ar = a.fcw + rw * HID;
        acc = 0.0f;
#pragma unroll 8
        for (int k = 0; k < HID; k++) acc = fmaf(ar[k], M[k * HID + col], acc);
    } else {
        acc = M[128 * HID + col];
#pragma unroll 8
        for (int k = 0; k < HID; k++) acc = fmaf(a.fcb[k], M[k * HID + col], acc);
    }
    o[i] = acc;
}

// ---------------- stage D: CSR scatter ----------------

__global__ void k_scatter(const int* __restrict__ ei, int* __restrict__ cursor,
                          int* __restrict__ csr) {
    int e = blockIdx.x * 256 + threadIdx.x;
    if (e < EE) {
        int d = ei[EE + e];
        int slot = atomicAdd(&cursor[d], 1);
        csr[slot] = ei[e];    // store src
    }
}

// ---------------- helpers ----------------

__device__ __forceinline__ float gather_row(const float* __restrict__ pre,
                                            const float* __restrict__ dinv,
                                            const int* __restrict__ offs,
                                            const int* __restrict__ csr,
                                            int row, int j) {
    float dd = dinv[row];
    float acc = pre[row * HID + j] * dd;
    int i = offs[row], e = offs[row + 1];
    for (; i + 3 < e; i += 4) {
        int s0 = csr[i], s1 = csr[i + 1], s2 = csr[i + 2], s3 = csr[i + 3];
        float a0 = pre[s0 * HID + j] * dinv[s0];
        float a1 = pre[s1 * HID + j] * dinv[s1];
        float a2 = pre[s2 * HID + j] * dinv[s2];
        float a3 = pre[s3 * HID + j] * dinv[s3];
        acc += (a0 + a1) + (a2 + a3);
    }
    for (; i < e; ++i) {
        int s = csr[i];
        acc += pre[s * HID + j] * dinv[s];
    }
    return acc * dd;
}

// layernorm for 2-rows-per-256-thread-block layout; sh = 8 floats scratch
__device__ __forceinline__ float rowln(float v, float w, float b, float* sh, int t) {
    int r = t >> 7;
    float s1 = v, s2 = v * v;
#pragma unroll
    for (int o = 32; o > 0; o >>= 1) {
        s1 += __shfl_down(s1, o);
        s2 += __shfl_down(s2, o);
    }
    int wv = (t >> 6) & 1;
    if ((t & 63) == 0) { sh[r * 4 + wv] = s1; sh[r * 4 + 2 + wv] = s2; }
    __syncthreads();
    float mean = (sh[r * 4] + sh[r * 4 + 1]) * (1.0f / HID);
    float m2   = (sh[r * 4 + 2] + sh[r * 4 + 3]) * (1.0f / HID);
    float rstd = rsqrtf(m2 - mean * mean + 1e-5f);
    float out = (v - mean) * rstd * w + b;
    __syncthreads();
    return out;
}

// ---------------- stage E: gather1 + bias/relu + GCN2 mm (row fused) ----------------

__global__ void k_gather_mm(const float* __restrict__ pre1, const float* __restrict__ dinv,
                            const int* __restrict__ offs, const int* __restrict__ csr,
                            const float* __restrict__ g1b, const float* __restrict__ g2w,
                            float* __restrict__ pre2) {
    __shared__ float sh_h[2][HID];
    int t = threadIdx.x, j = t & 127, r = t >> 7;
    int row = blockIdx.x * 2 + r;
    float g = gather_row(pre1, dinv, offs, csr, row, j);
    sh_h[r][j] = fmaxf(g + g1b[j], 0.0f);
    __syncthreads();
    float acc = 0.0f;
#pragma unroll 8
    for (int k = 0; k < HID; k++) acc = fmaf(sh_h[r][k], g2w[k * HID + j], acc);
    pre2[row * HID + j] = acc;
}

// ---------------- stage F: gather2 + ca0/ca1 + LN·LN -> t0 (row fused) ----------------

__global__ void k_row0(const float* __restrict__ pre2, const float* __restrict__ dinv,
                       const int* __restrict__ offs, const int* __restrict__ csr,
                       const float* __restrict__ g2b,
                       const float* __restrict__ Mfc0, const float* __restrict__ Mfc1,
                       const float* __restrict__ sa0bias,
                       const float* __restrict__ ln0w, const float* __restrict__ ln0b,
                       const float* __restrict__ ln1w, const float* __restrict__ ln1b,
                       float* __restrict__ ca1out, float* __restrict__ t0out) {
    __shared__ float sh_h[2][HID];
    __shared__ float shln[8];
    int t = threadIdx.x, j = t & 127, r = t >> 7;
    int row = blockIdx.x * 2 + r;
    float g = gather_row(pre2, dinv, offs, csr, row, j);
    sh_h[r][j] = fmaxf(g + g2b[j], 0.0f);
    __syncthreads();
    float a0 = Mfc0[128 * HID + j], a1 = Mfc1[128 * HID + j];
#pragma unroll 4
    for (int k = 0; k < HID; k++) {
        float hk = sh_h[r][k];
        a0 = fmaf(hk, Mfc0[k * HID + j], a0);
        a1 = fmaf(hk, Mfc1[k * HID + j], a1);
    }
    ca1out[row * HID + j] = a1;
    float v = rowln(sa0bias[j], ln0w[j], ln0b[j], shln, t);   // LN(tgt0 + sa0) row-const
    v = rowln(v + a0, ln1w[j], ln1b[j], shln, t);
    t0out[row * HID + j] = v;
}

// ---------------- stages G/I: fused FF (128->2048->128), split-K partials ----------------
// grid 512: kc = blk&7 owns mid cols [kc*256,+256); rg = blk>>3 owns rows [rg*8,+8)

__global__ void k_fff(const float* __restrict__ tin, const float* __restrict__ W1,
                      const float* __restrict__ b1, const float* __restrict__ W2,
                      float* __restrict__ part) {
    __shared__ float sh_t[8][HID];      // 4 KB
    __shared__ float sh_m[8][256];      // 8 KB
    int t = threadIdx.x;
    int kc = blockIdx.x & 7, rg = blockIdx.x >> 3;
    int row0 = rg * 8, c0 = kc * 256;
#pragma unroll
    for (int q = 0; q < 4; q++) {
        int i = q * 256 + t;
        sh_t[i >> 7][i & 127] = tin[row0 * HID + i];
    }
    __syncthreads();
    // phase 1: mid[8][256] = relu(t @ W1 + b1) on this column slice
    float acc[8];
    float bias = b1[c0 + t];
#pragma unroll
    for (int r = 0; r < 8; r++) acc[r] = bias;
#pragma unroll 4
    for (int k = 0; k < HID; k++) {
        float w = W1[k * FFD + c0 + t];
#pragma unroll
        for (int r = 0; r < 8; r++) acc[r] = fmaf(sh_t[r][k], w, acc[r]);
    }
#pragma unroll
    for (int r = 0; r < 8; r++) sh_m[r][t] = fmaxf(acc[r], 0.0f);
    __syncthreads();
    // phase 2: partial out[8][128] = mid @ W2 slice
    int col = t & 127, rr0 = (t >> 7) * 4;
    float a2[4] = {0.f, 0.f, 0.f, 0.f};
#pragma unroll 4
    for (int kk = 0; kk < 256; kk++) {
        float w = W2[(c0 + kk) * HID + col];
#pragma unroll
        for (int q = 0; q < 4; q++) a2[q] = fmaf(sh_m[rr0 + q][kk], w, a2[q]);
    }
#pragma unroll
    for (int q = 0; q < 4; q++)
        part[kc * (NN * HID) + (row0 + rr0 + q) * HID + col] = a2[q];
}

// ---------------- stage H: ff2 reduce + LN + sa1 + LN + LN -> t2 (row fused) ----------------

__global__ void k_row1(const float* __restrict__ part, const float* __restrict__ fb2,
                       const float* __restrict__ t0, const float* __restrict__ Msa1,
                       const float* __restrict__ ca1,
                       const float* __restrict__ ln2w, const float* __restrict__ ln2b,
                       const float* __restrict__ ln3w, const float* __restrict__ ln3b,
                       const float* __restrict__ ln4w, const float* __restrict__ ln4b,
                       float* __restrict__ t2out) {
    __shared__ float sh_t1[2][HID];
    __shared__ float shln[8];
    int t = threadIdx.x, j = t & 127, r = t >> 7;
    int row = blockIdx.x * 2 + r;
    float v = fb2[j] + t0[row * HID + j];
#pragma unroll
    for (int s = 0; s < 8; s++) v += part[s * (NN * HID) + row * HID + j];
    v = rowln(v, ln2w[j], ln2b[j], shln, t);          // t1
    sh_t1[r][j] = v;
    __syncthreads();
    float s1 = Msa1[128 * HID + j];
#pragma unroll 8
    for (int k = 0; k < HID; k++) s1 = fmaf(sh_t1[r][k], Msa1[k * HID + j], s1);
    float u = rowln(v + s1, ln3w[j], ln3b[j], shln, t);
    u = rowln(u + ca1[row * HID + j], ln4w[j], ln4b[j], shln, t);
    t2out[row * HID + j] = u;
}

// ---------------- stage J: ff2 reduce + LN + logits + broadcast ----------------

__global__ void k_rowout(const float* __restrict__ part, const float* __restrict__ fb2,
                         const float* __restrict__ t2,
                         const float* __restrict__ ln5w, const float* __restrict__ ln5b,
                         const float* __restrict__ ow, const float* __restrict__ ob,
                         float* __restrict__ out) {
    __shared__ float sh3[2][HID];
    __shared__ float shln[8];
    __shared__ float sh_lg[100];
    int t = threadIdx.x, j = t & 127, r = t >> 7;
    int row = blockIdx.x * 2 + r;
    float v = fb2[j] + t2[row * HID + j];
#pragma unroll
    for (int s = 0; s < 8; s++) v += part[s * (NN * HID) + row * HID + j];
    v = rowln(v, ln5w[j], ln5b[j], shln, t);
    sh3[r][j] = v;
    __syncthreads();
    if (j < VOCAB) {
        float acc = ob[j];
#pragma unroll 8
        for (int k = 0; k < HID; k++) acc = fmaf(sh3[r][k], ow[k * VOCAB + j], acc);
        sh_lg[r * VOCAB + j] = acc;
    }
    __syncthreads();
    int base = blockIdx.x * (2 * VOCAB);
    for (int idx = t; idx < SEQ * 2 * VOCAB; idx += 256) {
        int s = idx / (2 * VOCAB), p = idx - s * (2 * VOCAB);
        out[s * (NN * VOCAB) + base + p] = sh_lg[p];
    }
}

// ---------------- launch ----------------

extern "C" void kernel_launch(void* const* d_in, const int* in_sizes, int n_in,
                              void* d_out, int out_size, void* d_ws, size_t ws_size,
                              hipStream_t stream) {
    (void)in_sizes; (void)n_in; (void)out_size; (void)ws_size;
    const float* x   = (const float*)d_in[0];
    const int*   ei  = (const int*)d_in[1];
    const float* g1w = (const float*)d_in[2];
    const float* g1b = (const float*)d_in[3];
    const float* g2w = (const float*)d_in[4];
    const float* g2b = (const float*)d_in[5];
    const float* fcw = (const float*)d_in[6];
    const float* fcb = (const float*)d_in[7];
    const float* saw = (const float*)d_in[8];
    const float* sab = (const float*)d_in[9];
    const float* caw = (const float*)d_in[10];
    const float* cab = (const float*)d_in[11];
    const float* lnw = (const float*)d_in[12];
    const float* lnb = (const float*)d_in[13];
    const float* fw1 = (const float*)d_in[14];
    const float* fb1 = (const float*)d_in[15];
    const float* fw2 = (const float*)d_in[16];
    const float* fb2 = (const float*)d_in[17];
    const float* ow  = (const float*)d_in[18];
    const float* ob  = (const float*)d_in[19];
    float* out = (float*)d_out;

    // workspace layout (float offsets); total ~986K floats = 3.95 MB
    float* ws      = (float*)d_ws;
    float* qx      = ws;                 // 32768
    float* pre1    = ws + 32768;         // 65536
    float* pre2    = ws + 98304;         // 65536
    float* t0      = ws + 163840;        // 65536
    float* t2      = ws + 229376;        // 65536
    float* ca1     = ws + 294912;        // 65536
    float* Msa1    = ws + 360448;        // 16512
    float* Mca0    = ws + 376960;        // 16512
    float* Mca1    = ws + 393472;        // 16512
    float* Mfc0    = ws + 409984;        // 16512
    float* Mfc1    = ws + 426496;        // 16512
    float* sa0bias = ws + 443008;        // 128
    float* dinv    = ws + 443136;        // 512
    int*   cnt     = (int*)(ws + 443648);  // 512
    int*   offs    = cnt + 512;            // 513 (+pad)
    int*   cursor  = offs + 516;           // 512
    int*   csr     = cursor + 512;         // 16384
    float* part    = ws + 461824;        // 8*65536 = 524288

    // A
    k_prep<<<128, 256, 0, stream>>>(x, qx, cnt);

    // B: hist | mm1 | comb1(Msa1, Mca0, Mca1, sa0bias)
    {
        BArgs a;
        a.ei = ei; a.cnt = cnt; a.qx = qx; a.g1w = g1w; a.pre1 = pre1;
        a.A[0]  = saw + (4 + 2) * HID * HID;  a.ab[0] = sab + (4 + 2) * HID;
        a.Bm[0] = saw + (4 + 3) * HID * HID;  a.bb[0] = sab + (4 + 3) * HID;
        a.outM[0] = Msa1;
        a.A[1]  = caw + 2 * HID * HID;        a.ab[1] = cab + 2 * HID;
        a.Bm[1] = caw + 3 * HID * HID;        a.bb[1] = cab + 3 * HID;
        a.outM[1] = Mca0;
        a.A[2]  = caw + (4 + 2) * HID * HID;  a.ab[2] = cab + (4 + 2) * HID;
        a.Bm[2] = caw + (4 + 3) * HID * HID;  a.bb[2] = cab + (4 + 3) * HID;
        a.outM[2] = Mca1;
        a.ab3 = sab + 2 * HID;  a.B3 = saw + 3 * HID * HID;  a.bb3 = sab + 3 * HID;
        a.out3 = sa0bias;
        k_b<<<516, 256, 0, stream>>>(a);
    }

    // C: scan | comb2 (fold fc into Mca -> Mfc)
    {
        CArgs a;
        a.cnt = cnt; a.offs = offs; a.cursor = cursor; a.dinv = dinv;
        a.fcw = fcw; a.fcb = fcb;
        a.Mca0 = Mca0; a.Mca1 = Mca1; a.Mfc0 = Mfc0; a.Mfc1 = Mfc1;
        k_c<<<131, 256, 0, stream>>>(a);
    }

    // D
    k_scatter<<<64, 256, 0, stream>>>(ei, cursor, csr);

    // E: gather1 + relu + mm2
    k_gather_mm<<<256, 256, 0, stream>>>(pre1, dinv, offs, csr, g1b, g2w, pre2);

    // F: gather2 + ca0/ca1 + LN.LN -> t0
    k_row0<<<256, 256, 0, stream>>>(pre2, dinv, offs, csr, g2b, Mfc0, Mfc1, sa0bias,
                                    lnw + 0 * HID, lnb + 0 * HID,
                                    lnw + 1 * HID, lnb + 1 * HID, ca1, t0);

    // G: FF layer 0
    k_fff<<<512, 256, 0, stream>>>(t0, fw1, fb1, fw2, part);

    // H: reduce + LN2 + sa1 + LN3 + LN4 -> t2
    k_row1<<<256, 256, 0, stream>>>(part, fb2, t0, Msa1, ca1,
                                    lnw + 2 * HID, lnb + 2 * HID,
                                    lnw + 3 * HID, lnb + 3 * HID,
                                    lnw + 4 * HID, lnb + 4 * HID, t2);

    // I: FF layer 1
    k_fff<<<512, 256, 0, stream>>>(t2, fw1 + HID * FFD, fb1 + FFD, fw2 + FFD * HID, part);

    // J: reduce + LN5 + logits + broadcast
    k_rowout<<<256, 256, 0, stream>>>(part, fb2 + HID, t2,
                                      lnw + 5 * HID, lnb + 5 * HID, ow, ob, out);
}